// Round 1
// baseline (5216.626 us; speedup 1.0000x reference)
//
#include <hip/hip_runtime.h>
#include <cmath>

// n = m = 8192, d = 64, reg = 0.05, 20 Sinkhorn iterations
#define NPTS 8192
#define DIM  64
#define LOG2E 1.4426950408889634f
#define LA2   -13.0f   // log2(1/8192) exactly
#define NBLK  1024     // persistent grid: 4 blocks/CU x 256 CUs, all co-resident

typedef short s16x8  __attribute__((ext_vector_type(8)));   // 8 bf16
typedef float f32x16 __attribute__((ext_vector_type(16)));  // MFMA 32x32 acc

typedef __attribute__((address_space(1))) const unsigned char g8_t;
typedef __attribute__((address_space(3))) unsigned char l8_t;

#if __has_builtin(__builtin_amdgcn_exp2f)
__device__ __forceinline__ float exp2_fast(float x) { return __builtin_amdgcn_exp2f(x); }
#else
__device__ __forceinline__ float exp2_fast(float x) { return exp2f(x); }
#endif
#if __has_builtin(__builtin_amdgcn_logf)
__device__ __forceinline__ float log2_fast(float x) { return __builtin_amdgcn_logf(x); }
#else
__device__ __forceinline__ float log2_fast(float x) { return log2f(x); }
#endif

__device__ __forceinline__ unsigned short f2bf(float x) {
  unsigned u = __float_as_uint(x);
  return (unsigned short)((u + 0x7FFFu + ((u >> 16) & 1u)) >> 16);
}
__device__ __forceinline__ float bf2f(unsigned short b) {
  return __uint_as_float(((unsigned)b) << 16);
}

// ---------------------------------------------------------------------------
// prep: bf16 hi/lo split + squared row norms; init scal/out/barrier.
// ---------------------------------------------------------------------------
__global__ __launch_bounds__(256) void prep_kernel(
    const float* __restrict__ XP, const float* __restrict__ XQ,
    unsigned short* __restrict__ Phi, unsigned short* __restrict__ Plo,
    unsigned short* __restrict__ Qhi, unsigned short* __restrict__ Qlo,
    float* __restrict__ x2, float* __restrict__ y2,
    float* __restrict__ scal, float* __restrict__ out) {
  int gid  = blockIdx.x * 256 + threadIdx.x;
  int lane = threadIdx.x & 63;
  int row  = gid >> 6;            // 0..16383: P rows then Q rows (wave-uniform)
  int isP  = row < NPTS;
  int r    = row & (NPTS - 1);
  const float* X = isP ? XP : XQ;
  float x = X[r * DIM + lane];
  unsigned short h = f2bf(x);
  (isP ? Phi : Qhi)[r * DIM + lane] = h;
  (isP ? Plo : Qlo)[r * DIM + lane] = f2bf(x - bf2f(h));
  float s = x * x;
  for (int off = 32; off; off >>= 1) s += __shfl_down(s, off, 64);
  if (lane == 0) (isP ? x2 : y2)[r] = s;
  if (gid == 0) {
    ((unsigned*)scal)[0] = 0u;   // cmax bits
    ((unsigned*)scal)[4] = 0u;   // grid barrier counter
    out[0] = 0.0f;
  }
}

// ---------------------------------------------------------------------------
// software grid barrier (all NBLK blocks resident by construction:
// __launch_bounds__(256,4) caps VGPR<=128, LDS 37.4KB<40KB -> 4 blocks/CU).
// release: __threadfence writes back XCD L2; acquire: invalidates L1/L2.
// ---------------------------------------------------------------------------
__device__ __forceinline__ void grid_sync(unsigned* bar, unsigned target) {
  __syncthreads();                         // implicit vmcnt(0) drain
  if (threadIdx.x == 0) {
    __threadfence();
    __hip_atomic_fetch_add(bar, 1u, __ATOMIC_RELAXED, __HIP_MEMORY_SCOPE_AGENT);
    while (__hip_atomic_load(bar, __ATOMIC_RELAXED, __HIP_MEMORY_SCOPE_AGENT) < target)
      __builtin_amdgcn_s_sleep(2);
    __threadfence();
  }
  __syncthreads();
}

// ---------------------------------------------------------------------------
// one 128-col quarter of the 512-col panel: 4 ct steps of 32 cols.
// MODE 0: accS = max d2   MODE 1: racc[r] += 2^(C2L*dot + sCol[n])
// summation order over 32-col groups identical to the old half-based loop.
// ---------------------------------------------------------------------------
template <int MODE>
__device__ __forceinline__ void quarter(
    const short* __restrict__ buf, int qq, int g, int ln,
    const s16x8 (&a)[4], const float* __restrict__ sCol,
    const float* __restrict__ sY2, const float (&x2r)[16],
    float C2L, float (&racc)[16], float& accS) {
#pragma unroll 2
  for (int ct = 0; ct < 4; ++ct) {
    const int nn = ct * 32 + ln;       // row within quarter buffer
    const int n  = qq * 128 + nn;      // col within 512 panel
    s16x8 b[4];
#pragma unroll
    for (int ks = 0; ks < 4; ++ks)
      b[ks] = *(const s16x8*)(buf + nn * DIM + (((ks * 2 + g) ^ (ln & 7)) * 8));
    f32x16 acc;
#pragma unroll
    for (int r = 0; r < 16; ++r) acc[r] = 0.f;
#pragma unroll
    for (int ks = 0; ks < 4; ++ks)
      acc = __builtin_amdgcn_mfma_f32_32x32x16_bf16(a[ks], b[ks], acc, 0, 0, 0);
    if constexpr (MODE == 1) {
      const float bb = sCol[n];
#pragma unroll
      for (int r = 0; r < 16; ++r)
        racc[r] += exp2_fast(fmaf(C2L, acc[r], bb));
    } else {
      const float y2v = sY2[n];
#pragma unroll
      for (int r = 0; r < 16; ++r)
        accS = fmaxf(accS, fmaf(-2.0f, acc[r], x2r[r] + y2v));
    }
  }
}

// ---------------------------------------------------------------------------
// persistent kernel: cmax pass + 40 alternating u/v sweeps, grid-synced.
// B panels staged as 16KB quarters, double-buffered at issue/consume
// distance 1 (the vmcnt(0) at each barrier lands after a full compute
// phase -> no staging stall); next sweep's Q0 (= current A matrix, static
// data) prefetched during the last quarter, so every sweep starts hot.
// ---------------------------------------------------------------------------
__global__ __launch_bounds__(256, 4) void sinkhorn_kernel(
    const unsigned short* __restrict__ Phi, const unsigned short* __restrict__ Qhi,
    const float* __restrict__ x2, const float* __restrict__ y2,
    float* __restrict__ partU, float* __restrict__ partV,
    unsigned* __restrict__ scal) {
  __shared__ short sB[2][128 * DIM];   // 2 x 16KB quarter buffers, xor-swizzled
  __shared__ float sCol[512];
  __shared__ float sY2[512];
  __shared__ float sX2[128];
  __shared__ float sRed[4];

  const int t  = threadIdx.x;
  const int w  = t >> 6;
  const int l  = t & 63;
  const int g  = l >> 5;
  const int ln = l & 31;
  const int bx = blockIdx.x & 63;
  const int by = blockIdx.x >> 6;
  const int i0 = bx * 128;
  const int j0 = by * 512;
  unsigned* bar = scal + 4;
  unsigned gen = 0;

  // staging geometry: slot s = w*256 + c*64 + l holds (row = s>>3,
  // chunk cc = (s&7)^(row&7)); row&7 == l>>3, so cc is c-invariant.
  const int gOff   = (w * 32 + (l >> 3)) * 128 + (((l & 7) ^ (l >> 3)) * 16);
  const int ldsOff = w * 4096 + l * 16;

  auto stage = [&](const unsigned short* Bm, int qq, int bi) {
    const unsigned char* src =
        (const unsigned char*)(Bm + (size_t)(j0 + qq * 128) * DIM) + gOff;
    unsigned char* dst = (unsigned char*)(&sB[bi][0]) + ldsOff;
#pragma unroll
    for (int c = 0; c < 4; ++c)
      __builtin_amdgcn_global_load_lds((g8_t*)(src + c * 1024),
                                       (l8_t*)(dst + c * 1024), 16, 0, 0);
  };
  auto loadA = [&](const unsigned short* Am, s16x8 (&a)[4]) {
    const unsigned short* pa = Am + (size_t)(i0 + w * 32 + ln) * DIM + g * 8;
#pragma unroll
    for (int ks = 0; ks < 4; ++ks) a[ks] = *(const s16x8*)(pa + ks * 16);
  };

  float racc[16];
  float x2r[16];
  float invC, C2L;

  // ---- cmax pass (MODE 0): A = Phi rows, B = Qhi cols ----
  {
    stage(Qhi, 0, 0);
    stage(Qhi, 1, 1);
    s16x8 a[4];
    loadA(Phi, a);
#pragma unroll
    for (int c0 = 0; c0 < 2; ++c0) { int c = c0 * 256 + t; sY2[c] = y2[j0 + c]; }
    if (t < 128) sX2[t] = x2[i0 + t];
    __syncthreads();                        // drains Q0+Q1, publishes sX2/sY2
#pragma unroll
    for (int r = 0; r < 16; ++r)
      x2r[r] = sX2[w * 32 + (r & 3) + 8 * (r >> 2) + 4 * g];
    float accS = 0.f;
    quarter<0>(sB[0], 0, g, ln, a, sCol, sY2, x2r, 0.f, racc, accS);
    __syncthreads();
    stage(Qhi, 2, 0);
    quarter<0>(sB[1], 1, g, ln, a, sCol, sY2, x2r, 0.f, racc, accS);
    __syncthreads();                        // drains Q2
    stage(Qhi, 3, 1);
    quarter<0>(sB[0], 2, g, ln, a, sCol, sY2, x2r, 0.f, racc, accS);
    __syncthreads();                        // drains Q3
    stage(Qhi, 0, 0);                       // prefetch sweep-0 Q0 (B = Qhi too)
    quarter<0>(sB[1], 3, g, ln, a, sCol, sY2, x2r, 0.f, racc, accS);
#pragma unroll
    for (int off = 1; off < 64; off <<= 1)
      accS = fmaxf(accS, __shfl_xor(accS, off, 64));
    if (l == 0) sRed[w] = accS;
    __syncthreads();
    if (t == 0)
      atomicMax(scal, __float_as_uint(
          fmaxf(fmaxf(sRed[0], sRed[1]), fmaxf(sRed[2], sRed[3]))));
    ++gen;
    grid_sync(bar, gen * NBLK);
    if (t == 0)
      sRed[0] = __uint_as_float(
          __hip_atomic_load(scal, __ATOMIC_RELAXED, __HIP_MEMORY_SCOPE_AGENT));
    __syncthreads();
    float cmax = sRed[0];
    invC = 1.0f / (0.05f * cmax);
    C2L  = 2.0f * invC * LOG2E;
  }

  // ---- 40 sweeps: even = u-pass (A=Phi,B=Qhi), odd = v-pass (A=Qhi,B=Phi)
#pragma unroll 1
  for (int s = 0; s < 40; ++s) {
    const int e = s & 1;
    const unsigned short* Am = e ? Qhi : Phi;
    const unsigned short* Bm = e ? Phi : Qhi;
    const float* part = e ? partU : partV;
    float* outp = e ? partV : partU;

    stage(Bm, 1, 1);
    s16x8 a[4];
    loadA(Am, a);
    if (s == 0) {
#pragma unroll
      for (int c0 = 0; c0 < 2; ++c0) {
        int c = c0 * 256 + t;
        sCol[c] = -invC * sY2[c] * LOG2E;   // FIRST: v = 0 -> base from y2
      }
    } else {
#pragma unroll
      for (int c0 = 0; c0 < 2; ++c0) {
        int c = c0 * 256 + t;
        int jj = j0 + c;
        float ss = 0.f;
#pragma unroll
        for (int gy = 0; gy < 16; ++gy) ss += part[gy * NPTS + jj];
        sCol[c] = LA2 - log2_fast(ss);
      }
    }
    __syncthreads();                        // drains Q1 (Q0 prefetched earlier)
#pragma unroll
    for (int r = 0; r < 16; ++r) racc[r] = 0.f;
    float accS = 0.f;
    quarter<1>(sB[0], 0, g, ln, a, sCol, sY2, x2r, C2L, racc, accS);
    __syncthreads();
    stage(Bm, 2, 0);
    quarter<1>(sB[1], 1, g, ln, a, sCol, sY2, x2r, C2L, racc, accS);
    __syncthreads();                        // drains Q2
    stage(Bm, 3, 1);
    quarter<1>(sB[0], 2, g, ln, a, sCol, sY2, x2r, C2L, racc, accS);
    __syncthreads();                        // drains Q3
    if (s < 39) stage(Am, 0, 0);            // next sweep's B == current A
    quarter<1>(sB[1], 3, g, ln, a, sCol, sY2, x2r, C2L, racc, accS);
#pragma unroll
    for (int r = 0; r < 16; ++r) {
      float v = racc[r];
      v += __shfl_xor(v, 1, 64);
      v += __shfl_xor(v, 2, 64);
      v += __shfl_xor(v, 4, 64);
      v += __shfl_xor(v, 8, 64);
      v += __shfl_xor(v, 16, 64);
      if (ln == 0)
        outp[(size_t)by * NPTS + i0 + w * 32 +
             (r & 3) + 8 * (r >> 2) + 4 * g] = v;
    }
    if (s < 39) { ++gen; grid_sync(bar, gen * NBLK); }
  }
}

// ---------------------------------------------------------------------------
// final pass kernel (MODE 2 only): out += d2 * plan, hi+lo dot for C accuracy
// (kept identical to the verified kernel; other MODEs no longer instantiated)
// ---------------------------------------------------------------------------
template <int MODE, bool FIRST, int MINW>
__global__ __launch_bounds__(256, MINW) void pass_kernel(
    const unsigned short* __restrict__ Ahi, const unsigned short* __restrict__ Alo,
    const unsigned short* __restrict__ Bhi,
    const float* __restrict__ x2row, const float* __restrict__ y2col,
    const float* __restrict__ colPart, const float* __restrict__ rowPart,
    const unsigned* __restrict__ cmaxBits,
    float* __restrict__ outPart, float* __restrict__ outScalar) {
  __shared__ short sB[256 * DIM];   // 32 KB current half-panel, xor-swizzled
  __shared__ float sCol[512];
  __shared__ float sY2[512];
  __shared__ float sX2[128];
  __shared__ float sU2[128];
  __shared__ float sRed[4];

  const int t  = threadIdx.x;
  const int w  = t >> 6;
  const int l  = t & 63;
  const int g  = l >> 5;
  const int ln = l & 31;
  const int i0 = blockIdx.x * 128;
  const int j0 = blockIdx.y * 512;

  float invC = 0.f, C2L = 0.f;
  if constexpr (MODE != 0) {
    float cmax = __uint_as_float(*cmaxBits);
    invC = 1.0f / (0.05f * cmax);
    C2L  = 2.0f * invC * LOG2E;
  }

  const unsigned char* gB = (const unsigned char*)(Bhi + (size_t)j0 * DIM);
  const unsigned char* gsrc0;
  {
    int s   = w * 512 + l;
    int row = s >> 3;
    int cc  = (s & 7) ^ (row & 7);
    gsrc0 = gB + row * 128 + cc * 16;
  }
  auto stage = [&](int half) {
    const unsigned char* g0 = gsrc0 + half * 32768;
#pragma unroll
    for (int c = 0; c < 8; ++c)
      __builtin_amdgcn_global_load_lds(
          (g8_t*)(g0 + c * 1024),
          (l8_t*)((unsigned char*)sB + w * 8192 + c * 1024), 16, 0, 0);
  };

  s16x8 a_hi[4], a_lo[4];
  {
    const unsigned short* pa = Ahi + (size_t)(i0 + w * 32 + ln) * DIM + g * 8;
#pragma unroll
    for (int ks = 0; ks < 4; ++ks) a_hi[ks] = *(const s16x8*)(pa + ks * 16);
    if constexpr (MODE == 2) {
      const unsigned short* pb = Alo + (size_t)(i0 + w * 32 + ln) * DIM + g * 8;
#pragma unroll
      for (int ks = 0; ks < 4; ++ks) a_lo[ks] = *(const s16x8*)(pb + ks * 16);
    }
  }

  stage(0);

#pragma unroll
  for (int c0 = 0; c0 < 2; ++c0) {
    int c = c0 * 256 + t;
    int j = j0 + c;
    if constexpr (MODE == 0) {
      sY2[c] = y2col[j];
    } else if constexpr (MODE == 1) {
      if constexpr (FIRST) {
        sCol[c] = -invC * y2col[j] * LOG2E;
      } else {
        float s = 0.f;
#pragma unroll
        for (int gy = 0; gy < 16; ++gy) s += colPart[gy * NPTS + j];
        sCol[c] = LA2 - log2_fast(s);
      }
    } else {
      float s = 0.f;
#pragma unroll
      for (int gy = 0; gy < 16; ++gy) s += colPart[gy * NPTS + j];
      sCol[c] = LA2 - log2_fast(s);
      sY2[c] = y2col[j];
    }
  }
  if constexpr (MODE != 1) {
    if (t < 128) {
      sX2[t] = x2row[i0 + t];
      if constexpr (MODE == 2) {
        float s = 0.f;
#pragma unroll
        for (int gy = 0; gy < 16; ++gy) s += rowPart[gy * NPTS + i0 + t];
        sU2[t] = LA2 - log2_fast(s);
      }
    }
  }
  __syncthreads();

  float x2r2[16], u2r[16];
  if constexpr (MODE != 1) {
#pragma unroll
    for (int r = 0; r < 16; ++r) {
      int ri = w * 32 + (r & 3) + 8 * (r >> 2) + 4 * g;
      x2r2[r] = sX2[ri];
      if constexpr (MODE == 2) u2r[r] = sU2[ri];
    }
  }

  float racc[16];
#pragma unroll
  for (int r = 0; r < 16; ++r) racc[r] = 0.f;
  float accS = 0.f;

  for (int half = 0; half < 2; ++half) {
    if (half) {
      __syncthreads();
      stage(1);
      __syncthreads();
    }
#pragma unroll 2
    for (int ct = 0; ct < 8; ++ct) {
      const int nn = ct * 32 + ln;
      const int n  = half * 256 + nn;
      s16x8 b[4];
#pragma unroll
      for (int ks = 0; ks < 4; ++ks)
        b[ks] = *(const s16x8*)(sB + nn * DIM + (((ks * 2 + g) ^ (ln & 7)) * 8));
      f32x16 acc;
#pragma unroll
      for (int r = 0; r < 16; ++r) acc[r] = 0.f;
#pragma unroll
      for (int ks = 0; ks < 4; ++ks)
        acc = __builtin_amdgcn_mfma_f32_32x32x16_bf16(a_hi[ks], b[ks], acc, 0, 0, 0);

      if constexpr (MODE == 1) {
        float bb = sCol[n];
#pragma unroll
        for (int r = 0; r < 16; ++r)
          racc[r] += exp2_fast(fmaf(C2L, acc[r], bb));
      } else if constexpr (MODE == 0) {
        float y2v = sY2[n];
#pragma unroll
        for (int r = 0; r < 16; ++r)
          accS = fmaxf(accS, fmaf(-2.0f, acc[r], x2r2[r] + y2v));
      } else {
        f32x16 acc2;
#pragma unroll
        for (int r = 0; r < 16; ++r) acc2[r] = 0.f;
#pragma unroll
        for (int ks = 0; ks < 4; ++ks)
          acc2 = __builtin_amdgcn_mfma_f32_32x32x16_bf16(a_lo[ks], b[ks], acc2, 0, 0, 0);
        float y2v = sY2[n];
        float bb  = sCol[n];
#pragma unroll
        for (int r = 0; r < 16; ++r) {
          float dot = acc[r] + acc2[r];
          float d2  = fmaxf(fmaf(-2.0f, dot, x2r2[r] + y2v), 0.0f);
          accS = fmaf(d2, exp2_fast(fmaf(C2L, dot, u2r[r] + bb)), accS);
        }
      }
    }
  }

  if constexpr (MODE == 1) {
#pragma unroll
    for (int r = 0; r < 16; ++r) {
      float v = racc[r];
      v += __shfl_xor(v, 1, 64);
      v += __shfl_xor(v, 2, 64);
      v += __shfl_xor(v, 4, 64);
      v += __shfl_xor(v, 8, 64);
      v += __shfl_xor(v, 16, 64);
      if (ln == 0)
        outPart[blockIdx.y * NPTS + i0 + w * 32 +
                (r & 3) + 8 * (r >> 2) + 4 * g] = v;
    }
  } else {
    float v = accS;
#pragma unroll
    for (int off = 1; off < 64; off <<= 1) {
      float o = __shfl_xor(v, off, 64);
      v = (MODE == 0) ? fmaxf(v, o) : (v + o);
    }
    if (l == 0) sRed[w] = v;
    __syncthreads();
    if (t == 0) {
      float r0 = (MODE == 0) ? fmaxf(fmaxf(sRed[0], sRed[1]), fmaxf(sRed[2], sRed[3]))
                             : (sRed[0] + sRed[1] + sRed[2] + sRed[3]);
      if constexpr (MODE == 0)
        atomicMax((unsigned*)outScalar, __float_as_uint(r0));
      else
        atomicAdd(outScalar, r0);
    }
  }
}

// ---------------------------------------------------------------------------
extern "C" void kernel_launch(void* const* d_in, const int* in_sizes, int n_in,
                              void* d_out, int out_size, void* d_ws, size_t ws_size,
                              hipStream_t stream) {
  (void)in_sizes; (void)n_in; (void)out_size; (void)ws_size;
  const float* XP = (const float*)d_in[0];
  const float* XQ = (const float*)d_in[1];
  float* out = (float*)d_out;

  float* ws    = (float*)d_ws;
  float* x2    = ws;                        // 8192
  float* y2    = ws + 8192;                 // 8192
  float* partU = ws + 16384;                // 16 x 8192 (u-pass row sums)
  float* partV = partU + 16 * NPTS;         // 16 x 8192 (v-pass row sums)
  float* scal  = partV + 16 * NPTS;         // [0]=cmax bits, [4]=barrier
  unsigned short* Phi = (unsigned short*)(scal + 16);
  unsigned short* Plo = Phi + (size_t)NPTS * DIM;
  unsigned short* Qhi = Plo + (size_t)NPTS * DIM;
  unsigned short* Qlo = Qhi + (size_t)NPTS * DIM;   // total ws ~5.3 MB

  const unsigned* cmaxB = (const unsigned*)scal;

  prep_kernel<<<NPTS * 2 * DIM / 256, 256, 0, stream>>>(
      XP, XQ, Phi, Plo, Qhi, Qlo, x2, y2, scal, out);

  // persistent: cmax + all 40 Sinkhorn sweeps with software grid barriers
  sinkhorn_kernel<<<NBLK, 256, 0, stream>>>(
      Phi, Qhi, x2, y2, partU, partV, (unsigned*)scal);

  // final: sum C * plan (hi+lo dot for C accuracy)
  dim3 grid(NPTS / 128, NPTS / 512);        // (64, 16) = 1024 blocks
  pass_kernel<2, false, 2><<<grid, 256, 0, stream>>>(
      Phi, Plo, Qhi, x2, y2, partV, partU, cmaxB, nullptr, out);
}

// Round 2
// 820.181 us; speedup vs baseline: 6.3603x; 6.3603x over previous
//
#include <hip/hip_runtime.h>
#include <cmath>

// n = m = 8192, d = 64, reg = 0.05, 20 Sinkhorn iterations
#define NPTS 8192
#define DIM  64
#define LOG2E 1.4426950408889634f
#define LA2   -13.0f   // log2(1/8192) exactly

typedef short s16x8  __attribute__((ext_vector_type(8)));   // 8 bf16
typedef float f32x16 __attribute__((ext_vector_type(16)));  // MFMA 32x32 acc

typedef __attribute__((address_space(1))) const unsigned char g8_t;
typedef __attribute__((address_space(3))) unsigned char l8_t;

#if __has_builtin(__builtin_amdgcn_exp2f)
__device__ __forceinline__ float exp2_fast(float x) { return __builtin_amdgcn_exp2f(x); }
#else
__device__ __forceinline__ float exp2_fast(float x) { return exp2f(x); }
#endif
#if __has_builtin(__builtin_amdgcn_logf)
__device__ __forceinline__ float log2_fast(float x) { return __builtin_amdgcn_logf(x); }
#else
__device__ __forceinline__ float log2_fast(float x) { return log2f(x); }
#endif

__device__ __forceinline__ unsigned short f2bf(float x) {
  unsigned u = __float_as_uint(x);
  return (unsigned short)((u + 0x7FFFu + ((u >> 16) & 1u)) >> 16);
}
__device__ __forceinline__ float bf2f(unsigned short b) {
  return __uint_as_float(((unsigned)b) << 16);
}

// ---------------------------------------------------------------------------
// prep: bf16 hi/lo split + squared row norms; init scal/out. one wave per row.
// ---------------------------------------------------------------------------
__global__ __launch_bounds__(256) void prep_kernel(
    const float* __restrict__ XP, const float* __restrict__ XQ,
    unsigned short* __restrict__ Phi, unsigned short* __restrict__ Plo,
    unsigned short* __restrict__ Qhi, unsigned short* __restrict__ Qlo,
    float* __restrict__ x2, float* __restrict__ y2,
    float* __restrict__ scal, float* __restrict__ out) {
  int gid  = blockIdx.x * 256 + threadIdx.x;
  int lane = threadIdx.x & 63;
  int row  = gid >> 6;            // 0..16383: P rows then Q rows (wave-uniform)
  int isP  = row < NPTS;
  int r    = row & (NPTS - 1);
  const float* X = isP ? XP : XQ;
  float x = X[r * DIM + lane];
  unsigned short h = f2bf(x);
  (isP ? Phi : Qhi)[r * DIM + lane] = h;
  (isP ? Plo : Qlo)[r * DIM + lane] = f2bf(x - bf2f(h));
  float s = x * x;
  for (int off = 32; off; off >>= 1) s += __shfl_down(s, off, 64);
  if (lane == 0) (isP ? x2 : y2)[r] = s;
  if (gid == 0) { ((unsigned*)scal)[0] = 0u; out[0] = 0.0f; }
}

// ---------------------------------------------------------------------------
// pass_kernel<MODE, FIRST, MINW>: one (128 rows x 512 cols) tile sweep.
// B panel staged as FOUR 16 KB quarters (128 cols each), double-buffered in
// sB[2]; each 16 KB stage lands under a full quarter of compute (the
// vmcnt(0) implicit in __syncthreads drains it) -> no exposed mid-sweep
// staging stall (the old half-based loop fully serialized its second 32 KB).
// Column traversal order (ascending 32-col ct groups) is identical to the
// old half loop, so all accumulation orders are bitwise unchanged.
// MODE 0: cmax = max d2 (hi dot)                 -> atomicMax(uint) outScalar
// MODE 1: row sums of 2^(C2L*dot + b_j)          -> plain store outPart[gy][i]
// MODE 2: out += d2 * 2^(C2L*dot + bu_i + bv_j)  -> atomicAdd outScalar
// C/D layout (m74/m101): col = lane&31, row = (reg&3) + 8*(reg>>2) + 4*(lane>>5)
// ---------------------------------------------------------------------------
template <int MODE, bool FIRST, int MINW>
__global__ __launch_bounds__(256, MINW) void pass_kernel(
    const unsigned short* __restrict__ Ahi, const unsigned short* __restrict__ Alo,
    const unsigned short* __restrict__ Bhi,
    const float* __restrict__ x2row, const float* __restrict__ y2col,
    const float* __restrict__ colPart, const float* __restrict__ rowPart,
    const unsigned* __restrict__ cmaxBits,
    float* __restrict__ outPart, float* __restrict__ outScalar) {
  __shared__ short sB[2][128 * DIM];   // 2 x 16 KB quarter buffers, xor-swizzled
  __shared__ float sCol[512];          // per-col log2-domain base (modes 1,2)
  __shared__ float sY2[512];           // modes 0,2
  __shared__ float sX2[128];           // modes 0,2
  __shared__ float sU2[128];           // mode 2
  __shared__ float sRed[4];

  const int t  = threadIdx.x;
  const int w  = t >> 6;
  const int l  = t & 63;
  const int g  = l >> 5;
  const int ln = l & 31;
  const int i0 = blockIdx.x * 128;
  const int j0 = blockIdx.y * 512;

  float invC = 0.f, C2L = 0.f;
  if constexpr (MODE != 0) {
    float cmax = __uint_as_float(*cmaxBits);
    invC = 1.0f / (0.05f * cmax);
    C2L  = 2.0f * invC * LOG2E;
  }

  // staging geometry (verified r1): slot s = w*256 + c*64 + l holds
  // (row = s>>3, chunk cc = (s&7)^(row&7)); row&7 == l>>3 -> cc c-invariant.
  const int gOff   = (w * 32 + (l >> 3)) * 128 + (((l & 7) ^ (l >> 3)) * 16);
  const int ldsOff = w * 4096 + l * 16;
  auto stage = [&](int qq, int bi) {
    const unsigned char* src =
        (const unsigned char*)(Bhi + (size_t)(j0 + qq * 128) * DIM) + gOff;
    unsigned char* dst = (unsigned char*)(&sB[bi][0]) + ldsOff;
#pragma unroll
    for (int c = 0; c < 4; ++c)
      __builtin_amdgcn_global_load_lds((g8_t*)(src + c * 1024),
                                       (l8_t*)(dst + c * 1024), 16, 0, 0);
  };

  stage(0, 0);
  stage(1, 1);

  // A fragments: lane holds A[m=ln][k = ks*16 + g*8 + j]
  s16x8 a_hi[4], a_lo[4];
  {
    const unsigned short* pa = Ahi + (size_t)(i0 + w * 32 + ln) * DIM + g * 8;
#pragma unroll
    for (int ks = 0; ks < 4; ++ks) a_hi[ks] = *(const s16x8*)(pa + ks * 16);
    if constexpr (MODE == 2) {
      const unsigned short* pb = Alo + (size_t)(i0 + w * 32 + ln) * DIM + g * 8;
#pragma unroll
      for (int ks = 0; ks < 4; ++ks) a_lo[ks] = *(const s16x8*)(pb + ks * 16);
    }
  }

  // whole-panel column bases / norms (overlaps the in-flight staging)
#pragma unroll
  for (int c0 = 0; c0 < 2; ++c0) {
    int c = c0 * 256 + t;
    int j = j0 + c;
    if constexpr (MODE == 0) {
      sY2[c] = y2col[j];
    } else if constexpr (MODE == 1) {
      if constexpr (FIRST) {
        sCol[c] = -invC * y2col[j] * LOG2E;
      } else {
        float s = 0.f;
#pragma unroll
        for (int gy = 0; gy < 16; ++gy) s += colPart[gy * NPTS + j];
        sCol[c] = LA2 - log2_fast(s);
      }
    } else {
      float s = 0.f;
#pragma unroll
      for (int gy = 0; gy < 16; ++gy) s += colPart[gy * NPTS + j];
      sCol[c] = LA2 - log2_fast(s);
      sY2[c] = y2col[j];
    }
  }
  if constexpr (MODE != 1) {
    if (t < 128) {
      sX2[t] = x2row[i0 + t];
      if constexpr (MODE == 2) {
        float s = 0.f;
#pragma unroll
        for (int gy = 0; gy < 16; ++gy) s += rowPart[gy * NPTS + i0 + t];
        sU2[t] = LA2 - log2_fast(s);
      }
    }
  }
  __syncthreads();   // drains quarters 0+1 (vmcnt at barrier), publishes sCol/...

  float x2r[16], u2r[16];
  if constexpr (MODE != 1) {
#pragma unroll
    for (int r = 0; r < 16; ++r) {
      int ri = w * 32 + (r & 3) + 8 * (r >> 2) + 4 * g;
      x2r[r] = sX2[ri];
      if constexpr (MODE == 2) u2r[r] = sU2[ri];
    }
  }

  float racc[16];
#pragma unroll
  for (int r = 0; r < 16; ++r) racc[r] = 0.f;
  float accS = 0.f;

  // one 128-col quarter: 4 ct steps of 32 cols
  auto do_quarter = [&](const short* __restrict__ buf, int qq) {
#pragma unroll 2
    for (int ct = 0; ct < 4; ++ct) {
      const int nn = ct * 32 + ln;       // row within quarter buffer
      const int n  = qq * 128 + ct * 32 + ln;  // col within 512 panel
      s16x8 b[4];
#pragma unroll
      for (int ks = 0; ks < 4; ++ks)
        b[ks] = *(const s16x8*)(buf + nn * DIM + (((ks * 2 + g) ^ (ln & 7)) * 8));
      f32x16 acc;
#pragma unroll
      for (int r = 0; r < 16; ++r) acc[r] = 0.f;
#pragma unroll
      for (int ks = 0; ks < 4; ++ks)
        acc = __builtin_amdgcn_mfma_f32_32x32x16_bf16(a_hi[ks], b[ks], acc, 0, 0, 0);

      if constexpr (MODE == 1) {
        const float bb = sCol[n];
#pragma unroll
        for (int r = 0; r < 16; ++r)
          racc[r] += exp2_fast(fmaf(C2L, acc[r], bb));
      } else if constexpr (MODE == 0) {
        const float y2v = sY2[n];
#pragma unroll
        for (int r = 0; r < 16; ++r)
          accS = fmaxf(accS, fmaf(-2.0f, acc[r], x2r[r] + y2v));
      } else {
        f32x16 acc2;
#pragma unroll
        for (int r = 0; r < 16; ++r) acc2[r] = 0.f;
#pragma unroll
        for (int ks = 0; ks < 4; ++ks)
          acc2 = __builtin_amdgcn_mfma_f32_32x32x16_bf16(a_lo[ks], b[ks], acc2, 0, 0, 0);
        const float y2v = sY2[n];
        const float bb  = sCol[n];
#pragma unroll
        for (int r = 0; r < 16; ++r) {
          float dot = acc[r] + acc2[r];
          float d2  = fmaxf(fmaf(-2.0f, dot, x2r[r] + y2v), 0.0f);
          accS = fmaf(d2, exp2_fast(fmaf(C2L, dot, u2r[r] + bb)), accS);
        }
      }
    }
  };

  do_quarter(sB[0], 0);
  __syncthreads();               // all waves done reading b0
  stage(2, 0);                   // restage b0; lands under q1 compute
  do_quarter(sB[1], 1);
  __syncthreads();               // drains stage(2) + all reads of b1
  stage(3, 1);                   // restage b1; lands under q2 compute
  do_quarter(sB[0], 2);
  __syncthreads();               // drains stage(3)
  do_quarter(sB[1], 3);

  if constexpr (MODE == 1) {
    // reduce each acc row over its 32 cols (stays within the g-half), store
#pragma unroll
    for (int r = 0; r < 16; ++r) {
      float v = racc[r];
      v += __shfl_xor(v, 1, 64);
      v += __shfl_xor(v, 2, 64);
      v += __shfl_xor(v, 4, 64);
      v += __shfl_xor(v, 8, 64);
      v += __shfl_xor(v, 16, 64);
      if (ln == 0)
        outPart[blockIdx.y * NPTS + i0 + w * 32 +
                (r & 3) + 8 * (r >> 2) + 4 * g] = v;
    }
  } else {
    float v = accS;
#pragma unroll
    for (int off = 1; off < 64; off <<= 1) {
      float o = __shfl_xor(v, off, 64);
      v = (MODE == 0) ? fmaxf(v, o) : (v + o);
    }
    if (l == 0) sRed[w] = v;
    __syncthreads();
    if (t == 0) {
      float r0 = (MODE == 0) ? fmaxf(fmaxf(sRed[0], sRed[1]), fmaxf(sRed[2], sRed[3]))
                             : (sRed[0] + sRed[1] + sRed[2] + sRed[3]);
      if constexpr (MODE == 0)
        atomicMax((unsigned*)outScalar, __float_as_uint(r0));
      else
        atomicAdd(outScalar, r0);
    }
  }
}

// ---------------------------------------------------------------------------
extern "C" void kernel_launch(void* const* d_in, const int* in_sizes, int n_in,
                              void* d_out, int out_size, void* d_ws, size_t ws_size,
                              hipStream_t stream) {
  (void)in_sizes; (void)n_in; (void)out_size; (void)ws_size;
  const float* XP = (const float*)d_in[0];
  const float* XQ = (const float*)d_in[1];
  float* out = (float*)d_out;

  float* ws    = (float*)d_ws;
  float* x2    = ws;                        // 8192
  float* y2    = ws + 8192;                 // 8192
  float* partU = ws + 16384;                // 16 x 8192 (u-pass row sums)
  float* partV = partU + 16 * NPTS;         // 16 x 8192 (v-pass row sums)
  float* scal  = partV + 16 * NPTS;         // [0] = cmax bits (16 reserved)
  unsigned short* Phi = (unsigned short*)(scal + 16);
  unsigned short* Plo = Phi + (size_t)NPTS * DIM;
  unsigned short* Qhi = Plo + (size_t)NPTS * DIM;
  unsigned short* Qlo = Qhi + (size_t)NPTS * DIM;   // total ws ~5.3 MB

  const unsigned* cmaxB = (const unsigned*)scal;
  dim3 grid(NPTS / 128, NPTS / 512);        // (64, 16) = 1024 blocks

  prep_kernel<<<NPTS * 2 * DIM / 256, 256, 0, stream>>>(
      XP, XQ, Phi, Plo, Qhi, Qlo, x2, y2, scal, out);

  // Cmax (hi-only: |err| ~1e-4 relative, shifts effective reg negligibly)
  pass_kernel<0, false, 4><<<grid, 256, 0, stream>>>(
      Phi, nullptr, Qhi, x2, y2, nullptr, nullptr, cmaxB, nullptr, scal);

  // iter 1: u-pass with v = 0 (base from y2), then v-pass from partU
  pass_kernel<1, true, 4><<<grid, 256, 0, stream>>>(
      Phi, nullptr, Qhi, nullptr, y2, nullptr, nullptr, cmaxB, partU, nullptr);
  pass_kernel<1, false, 4><<<grid, 256, 0, stream>>>(
      Qhi, nullptr, Phi, nullptr, nullptr, partU, nullptr, cmaxB, partV, nullptr);

  for (int it = 1; it < 20; ++it) {
    pass_kernel<1, false, 4><<<grid, 256, 0, stream>>>(
        Phi, nullptr, Qhi, nullptr, nullptr, partV, nullptr, cmaxB, partU, nullptr);
    pass_kernel<1, false, 4><<<grid, 256, 0, stream>>>(
        Qhi, nullptr, Phi, nullptr, nullptr, partU, nullptr, cmaxB, partV, nullptr);
  }

  // final: sum C * plan (hi+lo dot for C accuracy)
  pass_kernel<2, false, 2><<<grid, 256, 0, stream>>>(
      Phi, Plo, Qhi, x2, y2, partV, partU, cmaxB, nullptr, out);
}